// Round 1
// baseline (208.596 us; speedup 1.0000x reference)
//
#include <hip/hip_runtime.h>
#include <math.h>

#define M_ 4
#define B_ 8192
#define C_ 1000
#define NROWS (M_ * B_)
#define LOGC 6.907755278982137f  // ln(1000)

// ---------------------------------------------------------------------------
// Kernel 1: per-row (m,b) stats. One 64-lane wave per row, 4 waves per block.
// Each lane holds up to 4 float4 (16 floats); two register passes (max, then
// sum + sumexp). Row length 1000 = 250 float4, 16B-aligned (1000 % 4 == 0).
// ---------------------------------------------------------------------------
__global__ __launch_bounds__(256) void stats_kernel(
    const float* __restrict__ logits, const int* __restrict__ targets,
    float* __restrict__ ce_arr, float* __restrict__ ent_arr) {
  const int wave = threadIdx.x >> 6;
  const int lane = threadIdx.x & 63;
  const int row = blockIdx.x * 4 + wave;  // row = m*B + b (matches layout)
  if (row >= NROWS) return;

  const float* rowp = logits + (size_t)row * C_;
  const float4* p = (const float4*)rowp;

  float4 v[4];
#pragma unroll
  for (int k = 0; k < 4; ++k) {
    int idx = lane + 64 * k;
    if (k < 3 || idx < 250) {
      v[k] = p[idx];
    } else {
      v[k] = make_float4(0.f, 0.f, 0.f, 0.f);  // ignored via valid-count below
    }
  }
  const int nvalid = (lane < 58) ? 4 : 3;  // lane+192 < 250 iff lane < 58

  // pass 1: row max
  float lmax = -INFINITY;
#pragma unroll
  for (int k = 0; k < 4; ++k) {
    if (k < nvalid) {
      lmax = fmaxf(lmax, fmaxf(fmaxf(v[k].x, v[k].y), fmaxf(v[k].z, v[k].w)));
    }
  }
#pragma unroll
  for (int off = 32; off; off >>= 1) lmax = fmaxf(lmax, __shfl_xor(lmax, off));

  // pass 2: sum(x) and sum(exp(x - max))
  float lsum = 0.f, lexp = 0.f;
#pragma unroll
  for (int k = 0; k < 4; ++k) {
    if (k < nvalid) {
      lsum += (v[k].x + v[k].y) + (v[k].z + v[k].w);
      lexp += __expf(v[k].x - lmax) + __expf(v[k].y - lmax) +
              __expf(v[k].z - lmax) + __expf(v[k].w - lmax);
    }
  }
#pragma unroll
  for (int off = 32; off; off >>= 1) {
    lsum += __shfl_xor(lsum, off);
    lexp += __shfl_xor(lexp, off);
  }

  if (lane == 0) {
    const int b = row & (B_ - 1);
    const float lse = lmax + __logf(lexp);
    const float tval = rowp[targets[b]];
    ce_arr[row] = lse - tval;                         // -logp[target]
    ent_arr[row] = lse - lsum * (1.0f / C_) - LOGC;   // -log C - mean(logp)
  }
}

// ---------------------------------------------------------------------------
// Kernel 2: per-sample argmin over M models + scalar loss reduction.
// loss[m] = ce[m] + (total_ent - ent[m])   (BETA = 1)
// new_loss contribution per b: (ce[win] - ent[win] + total_ent) / B
// ---------------------------------------------------------------------------
__global__ __launch_bounds__(256) void argmin_kernel(
    const float* __restrict__ ce_arr, const float* __restrict__ ent_arr,
    float* __restrict__ out, int* __restrict__ win_arr) {
  const int b = blockIdx.x * 256 + threadIdx.x;

  float ce[M_], ent[M_], tot = 0.f;
#pragma unroll
  for (int m = 0; m < M_; ++m) {
    ce[m] = ce_arr[m * B_ + b];
    ent[m] = ent_arr[m * B_ + b];
    tot += ent[m];
  }
  float best = ce[0] + (tot - ent[0]);
  int bi = 0;
#pragma unroll
  for (int m = 1; m < M_; ++m) {
    float l = ce[m] + (tot - ent[m]);
    if (l < best) { best = l; bi = m; }  // strict <: first-min tie-break
  }
  win_arr[b] = bi;
  out[1 + (size_t)B_ * C_ + b] = (float)bi;  // min_index as float

  float contrib = (ce[bi] - ent[bi] + tot) * (1.0f / B_);
#pragma unroll
  for (int off = 32; off; off >>= 1) contrib += __shfl_xor(contrib, off);

  __shared__ float red[4];
  if ((threadIdx.x & 63) == 0) red[threadIdx.x >> 6] = contrib;
  __syncthreads();
  if (threadIdx.x == 0) {
    atomicAdd(out, (red[0] + red[1]) + (red[2] + red[3]));
  }
}

// ---------------------------------------------------------------------------
// Kernel 3: oracle gather — copy winner row b to d_out. Scalar stores because
// the oracle region starts at element offset 1 (4B-misaligned for float4).
// ---------------------------------------------------------------------------
__global__ __launch_bounds__(256) void gather_kernel(
    const float* __restrict__ logits, const int* __restrict__ win_arr,
    float* __restrict__ out) {
  const int b = blockIdx.x;
  const int win = win_arr[b];
  const float* src = logits + ((size_t)win * B_ + b) * C_;
  float* dst = out + 1 + (size_t)b * C_;
  for (int t = threadIdx.x; t < C_; t += 256) dst[t] = src[t];
}

extern "C" void kernel_launch(void* const* d_in, const int* in_sizes, int n_in,
                              void* d_out, int out_size, void* d_ws,
                              size_t ws_size, hipStream_t stream) {
  const float* logits = (const float*)d_in[0];
  const int* targets = (const int*)d_in[1];
  float* out = (float*)d_out;

  float* ce_arr = (float*)d_ws;            // M*B floats
  float* ent_arr = ce_arr + NROWS;         // M*B floats
  int* win_arr = (int*)(ent_arr + NROWS);  // B ints

  hipMemsetAsync(d_out, 0, sizeof(float), stream);  // zero the scalar accum

  stats_kernel<<<NROWS / 4, 256, 0, stream>>>(logits, targets, ce_arr, ent_arr);
  argmin_kernel<<<B_ / 256, 256, 0, stream>>>(ce_arr, ent_arr, out, win_arr);
  gather_kernel<<<B_, 256, 0, stream>>>(logits, win_arr, out);
}

// Round 2
// 197.704 us; speedup vs baseline: 1.0551x; 1.0551x over previous
//
#include <hip/hip_runtime.h>
#include <math.h>

#define M_ 4
#define B_ 8192
#define C_ 1000
#define LOGC 6.907755278982137f  // ln(1000)

// ---------------------------------------------------------------------------
// Fused kernel: one block per sample b; wave m (of 4) owns row (m, b).
//  - each wave: float4 loads (row fully register-resident), shuffle-reduce
//    max, then sum + sumexp  ->  ce[m], ent[m] in LDS
//  - thread 0: argmin over the 4 losses, writes min_index (as float) and the
//    per-sample scalar partial to ws
//  - winning wave: writes its register-held row to out (oracle_logits) —
//    no second read of logits from HBM.
// Traffic: 131 MB read + 32.8 MB write, vs 197 MB in the 3-kernel version.
// ---------------------------------------------------------------------------
__global__ __launch_bounds__(256) void fused_kernel(
    const float* __restrict__ logits, const int* __restrict__ targets,
    float* __restrict__ out, float* __restrict__ partials) {
  const int b = blockIdx.x;
  const int m = threadIdx.x >> 6;  // wave index == model index
  const int lane = threadIdx.x & 63;

  const float* rowp = logits + ((size_t)m * B_ + b) * C_;
  const float4* p = (const float4*)rowp;  // 1000 % 4 == 0, 16B-aligned

  float4 v[4];
#pragma unroll
  for (int k = 0; k < 4; ++k) {
    const int idx = lane + 64 * k;
    if (k < 3 || idx < 250) {
      v[k] = p[idx];
    } else {
      v[k] = make_float4(0.f, 0.f, 0.f, 0.f);
    }
  }
  const int nvalid = (lane < 58) ? 4 : 3;  // lane+192 < 250 iff lane < 58

  // row max
  float lmax = -INFINITY;
#pragma unroll
  for (int k = 0; k < 4; ++k)
    if (k < nvalid)
      lmax = fmaxf(lmax, fmaxf(fmaxf(v[k].x, v[k].y), fmaxf(v[k].z, v[k].w)));
#pragma unroll
  for (int off = 32; off; off >>= 1) lmax = fmaxf(lmax, __shfl_xor(lmax, off));

  // sum(x), sum(exp(x - max))
  float lsum = 0.f, lexp = 0.f;
#pragma unroll
  for (int k = 0; k < 4; ++k) {
    if (k < nvalid) {
      lsum += (v[k].x + v[k].y) + (v[k].z + v[k].w);
      lexp += __expf(v[k].x - lmax) + __expf(v[k].y - lmax) +
              __expf(v[k].z - lmax) + __expf(v[k].w - lmax);
    }
  }
#pragma unroll
  for (int off = 32; off; off >>= 1) {
    lsum += __shfl_xor(lsum, off);
    lexp += __shfl_xor(lexp, off);
  }

  __shared__ float s_ce[M_], s_ent[M_];
  __shared__ int s_win;
  if (lane == 0) {
    const float lse = lmax + __logf(lexp);
    s_ce[m] = lse - rowp[targets[b]];              // -logp[target]
    s_ent[m] = lse - lsum * (1.0f / C_) - LOGC;    // -log C - mean(logp)
  }
  __syncthreads();

  if (threadIdx.x == 0) {
    const float tot = (s_ent[0] + s_ent[1]) + (s_ent[2] + s_ent[3]);
    float best = s_ce[0] + (tot - s_ent[0]);
    int bi = 0;
#pragma unroll
    for (int j = 1; j < M_; ++j) {
      const float l = s_ce[j] + (tot - s_ent[j]);
      if (l < best) { best = l; bi = j; }  // strict <: first-min tie-break
    }
    s_win = bi;
    out[1 + (size_t)B_ * C_ + b] = (float)bi;               // min_index
    partials[b] = (s_ce[bi] - s_ent[bi] + tot) * (1.0f / B_);  // scalar part
  }
  __syncthreads();

  // winning wave writes its register-held row (oracle_logits). Scalar dword
  // stores: region starts at out+1 (float4-misaligned); runs are contiguous
  // per wave so L2 write-combining keeps near-full line efficiency.
  if (m == s_win) {
    float* dst = out + 1 + (size_t)b * C_;
#pragma unroll
    for (int k = 0; k < 4; ++k) {
      const int idx = lane + 64 * k;
      if (k < 3 || idx < 250) {
        const int e = 4 * idx;
        dst[e + 0] = v[k].x;
        dst[e + 1] = v[k].y;
        dst[e + 2] = v[k].z;
        dst[e + 3] = v[k].w;
      }
    }
  }
}

// ---------------------------------------------------------------------------
// Final reduce: sum B partials -> out[0]. Single block, plain store (no
// memset / atomics needed).
// ---------------------------------------------------------------------------
__global__ __launch_bounds__(1024) void reduce_kernel(
    const float* __restrict__ partials, float* __restrict__ out) {
  const float4* p4 = (const float4*)partials;  // B/4 = 2048 float4
  float s = 0.f;
#pragma unroll
  for (int k = 0; k < 2; ++k) {
    const float4 v = p4[threadIdx.x + 1024 * k];
    s += (v.x + v.y) + (v.z + v.w);
  }
#pragma unroll
  for (int off = 32; off; off >>= 1) s += __shfl_xor(s, off);

  __shared__ float red[16];
  if ((threadIdx.x & 63) == 0) red[threadIdx.x >> 6] = s;
  __syncthreads();
  if (threadIdx.x < 16) {
    float t = red[threadIdx.x];
#pragma unroll
    for (int off = 8; off; off >>= 1) t += __shfl_xor(t, off, 16);
    if (threadIdx.x == 0) out[0] = t;
  }
}

extern "C" void kernel_launch(void* const* d_in, const int* in_sizes, int n_in,
                              void* d_out, int out_size, void* d_ws,
                              size_t ws_size, hipStream_t stream) {
  const float* logits = (const float*)d_in[0];
  const int* targets = (const int*)d_in[1];
  float* out = (float*)d_out;
  float* partials = (float*)d_ws;  // B floats

  fused_kernel<<<B_, 256, 0, stream>>>(logits, targets, out, partials);
  reduce_kernel<<<1, 1024, 0, stream>>>(partials, out);
}